// Round 1
// baseline (29323.425 us; speedup 1.0000x reference)
//
#include <hip/hip_runtime.h>
#include <hip/hip_bf16.h>

#define H 512
#define TSTEPS 100
#define BATCH 512

__device__ inline float sigmoidf_(float x) { return 1.0f / (1.0f + __expf(-x)); }
__device__ inline float ftanh(float x) {
    x = fminf(15.0f, fmaxf(-15.0f, x));
    float e = __expf(2.0f * x);
    return (e - 1.0f) / (e + 1.0f);
}
__device__ inline float bf2f(unsigned short u) {
    union { unsigned int i; float f; } z; z.i = ((unsigned int)u) << 16; return z.f;
}

// ---------------- prep: W_comb = enc_Wih @ W_emb, combined biases ----------------
__global__ void prep_kernel(const float* __restrict__ W_emb, const float* __restrict__ enc_Wih,
                            const float* __restrict__ enc_bih, const float* __restrict__ enc_bhh,
                            const float* __restrict__ dec_bih, const float* __restrict__ dec_bhh,
                            float* __restrict__ Wc, float* __restrict__ bc, float* __restrict__ db) {
    int g = blockIdx.x * blockDim.x + threadIdx.x;
    if (g >= 4 * H) return;
    float s0 = 0.f, s1 = 0.f;
    for (int j = 0; j < H; ++j) {
        float w = enc_Wih[(size_t)g * H + j];
        s0 += w * W_emb[j * 2 + 0];
        s1 += w * W_emb[j * 2 + 1];
    }
    Wc[g * 2 + 0] = s0; Wc[g * 2 + 1] = s1;
    bc[g] = enc_bih[g] + enc_bhh[g];
    db[g] = dec_bih[g] + dec_bhh[g];
}

__global__ void zero_kernel(float* __restrict__ p, int n) {
    int i = blockIdx.x * blockDim.x + threadIdx.x;
    if (i < n) p[i] = 0.f;
}

// ---------------- LSTM step (enc: gates = h@Whh.T + x-part; dec: dec_i@Wih.T + h@Whh.T) ----
#define BMT 32
#define KCT 32

template <int IS_ENC>
__global__ __launch_bounds__(256) void lstm_step(
    const float* __restrict__ xin,    // enc: x (B,T,2); dec: input (B,H)
    const float* __restrict__ hprev,  // (B,H)
    const float* __restrict__ Wih,    // enc: Wc (4H,2); dec: dec_Wih (4H,H)
    const float* __restrict__ Whh,    // (4H,H)
    const float* __restrict__ bias,   // (4H)
    float* __restrict__ cbuf,         // (B,H) in-place
    float* __restrict__ hnext,        // (B,H)
    __hip_bfloat16* __restrict__ ench,// enc: enc_h slice for this t (B,H); dec: null
    int t) {
    __shared__ float hs[KCT][BMT + 2];
    __shared__ float ws[4][KCT][BMT + 2];
    const int tid = threadIdx.x;
    const int tx = tid & 15, ty = tid >> 4;
    const int bm = blockIdx.x, bn = blockIdx.y;
    float acc[4][2][2] = {};
    const int nph = IS_ENC ? 1 : 2;
    for (int ph = 0; ph < nph; ++ph) {
        const float* A = (IS_ENC || ph == 1) ? hprev : xin;
        const float* W = (IS_ENC || ph == 1) ? Whh : Wih;
        for (int k0 = 0; k0 < H; k0 += KCT) {
            for (int i = tid; i < BMT * KCT; i += 256) {
                int r = i >> 5, col = i & 31;
                hs[col][r] = A[(size_t)(bm * BMT + r) * H + k0 + col];
            }
            for (int i = tid; i < 4 * BMT * KCT; i += 256) {
                int q = i >> 10, rem = i & 1023;
                int r = rem >> 5, col = rem & 31;
                ws[q][col][r] = W[(size_t)(q * H + bn * BMT + r) * H + k0 + col];
            }
            __syncthreads();
#pragma unroll 8
            for (int kk = 0; kk < KCT; ++kk) {
                float2 av = *(const float2*)&hs[kk][ty * 2];
#pragma unroll
                for (int q = 0; q < 4; ++q) {
                    float2 bv = *(const float2*)&ws[q][kk][tx * 2];
                    acc[q][0][0] += av.x * bv.x; acc[q][0][1] += av.x * bv.y;
                    acc[q][1][0] += av.y * bv.x; acc[q][1][1] += av.y * bv.y;
                }
            }
            __syncthreads();
        }
    }
#pragma unroll
    for (int bi = 0; bi < 2; ++bi) {
        int b = bm * BMT + ty * 2 + bi;
        float x0 = 0.f, x1 = 0.f;
        if (IS_ENC) {
            x0 = xin[(size_t)(b * TSTEPS + t) * 2 + 0];
            x1 = xin[(size_t)(b * TSTEPS + t) * 2 + 1];
        }
#pragma unroll
        for (int ni = 0; ni < 2; ++ni) {
            int n = bn * BMT + tx * 2 + ni;
            float g[4];
#pragma unroll
            for (int q = 0; q < 4; ++q) {
                g[q] = acc[q][bi][ni] + bias[q * H + n];
                if (IS_ENC)
                    g[q] += x0 * Wih[(size_t)(q * H + n) * 2 + 0] + x1 * Wih[(size_t)(q * H + n) * 2 + 1];
            }
            float ig = sigmoidf_(g[0]), fg = sigmoidf_(g[1]);
            float gg = ftanh(g[2]), og = sigmoidf_(g[3]);
            size_t idx = (size_t)b * H + n;
            float cn = fg * cbuf[idx] + ig * gg;
            float hn = og * ftanh(cn);
            cbuf[idx] = cn;
            hnext[idx] = hn;
            if (IS_ENC) ench[idx] = __float2bfloat16(hn);
        }
    }
}

// ---------------- generic 32x32 tiled GEMM: O = A @ B.T (B is N x K row-major) ----------
template <int ABF, int OBF>
__global__ __launch_bounds__(256) void gemm_nt32(const void* __restrict__ Ap,
                                                 const float* __restrict__ Bp,
                                                 void* __restrict__ Op, int K) {
    __shared__ float as_[KCT][BMT + 2];
    __shared__ float bs_[KCT][BMT + 2];
    const int tid = threadIdx.x;
    const int tx = tid & 15, ty = tid >> 4;
    const size_t m0 = (size_t)blockIdx.x * 32, n0 = (size_t)blockIdx.y * 32;
    const int N = gridDim.y * 32;
    float acc[2][2] = {};
    for (int k0 = 0; k0 < K; k0 += KCT) {
        for (int i = tid; i < 32 * 32; i += 256) {
            int r = i >> 5, col = i & 31;
            float aval;
            if (ABF)
                aval = bf2f(((const unsigned short*)Ap)[(m0 + r) * (size_t)K + k0 + col]);
            else
                aval = ((const float*)Ap)[(m0 + r) * (size_t)K + k0 + col];
            as_[col][r] = aval;
            bs_[col][r] = Bp[(n0 + r) * (size_t)K + k0 + col];
        }
        __syncthreads();
#pragma unroll 8
        for (int kk = 0; kk < KCT; ++kk) {
            float2 av = *(const float2*)&as_[kk][ty * 2];
            float2 bv = *(const float2*)&bs_[kk][tx * 2];
            acc[0][0] += av.x * bv.x; acc[0][1] += av.x * bv.y;
            acc[1][0] += av.y * bv.x; acc[1][1] += av.y * bv.y;
        }
        __syncthreads();
    }
#pragma unroll
    for (int bi = 0; bi < 2; ++bi)
#pragma unroll
        for (int ni = 0; ni < 2; ++ni) {
            size_t oidx = (m0 + ty * 2 + bi) * (size_t)N + n0 + tx * 2 + ni;
            if (OBF)
                ((__hip_bfloat16*)Op)[oidx] = __float2bfloat16(acc[bi][ni]);
            else
                ((float*)Op)[oidx] = acc[bi][ni];
        }
}

// ---------------- attention: u = v.tanh(u1+u2), softmax over c, d = a@enc_h -----------
__global__ __launch_bounds__(256) void attn_step(const float* __restrict__ u2,
                                                 const __hip_bfloat16* __restrict__ u1,
                                                 const __hip_bfloat16* __restrict__ ench,
                                                 const float* __restrict__ vv,
                                                 float* __restrict__ deci) {
    __shared__ float su2[2][2][TSTEPS];
    __shared__ float su[2][TSTEPS];
    const int tid = threadIdx.x;
    const int r = tid >> 7;        // batch row within tile (0..1)
    const int l = tid & 127;       // 128 threads per row, 4 h each
    const int b = blockIdx.x * 2 + r;
    const int w = (tid >> 6) & 1;  // wave within row
    const float4 u2r = *reinterpret_cast<const float4*>(&u2[(size_t)b * H + l * 4]);
    const float4 vr = *reinterpret_cast<const float4*>(&vv[l * 4]);
    const unsigned short* u1s = reinterpret_cast<const unsigned short*>(u1);
    const unsigned short* ehs = reinterpret_cast<const unsigned short*>(ench);

    for (int cc = 0; cc < TSTEPS; ++cc) {
        ushort4 uv = *reinterpret_cast<const ushort4*>(&u1s[((size_t)cc * BATCH + b) * H + l * 4]);
        float p = vr.x * ftanh(bf2f(uv.x) + u2r.x)
                + vr.y * ftanh(bf2f(uv.y) + u2r.y)
                + vr.z * ftanh(bf2f(uv.z) + u2r.z)
                + vr.w * ftanh(bf2f(uv.w) + u2r.w);
#pragma unroll
        for (int off = 32; off; off >>= 1) p += __shfl_xor(p, off);
        if ((tid & 63) == 0) su2[r][w][cc] = p;
    }
    __syncthreads();
    if (((tid >> 6) & 1) == 0) {   // waves 0 and 2 do softmax for rows 0 and 1
        const int rr = tid >> 7;
        const int lane = tid & 63;
        const int c2 = lane + 64;
        float s1 = su2[rr][0][lane] + su2[rr][1][lane];
        float s2 = (c2 < TSTEPS) ? (su2[rr][0][c2] + su2[rr][1][c2]) : -1e30f;
        float m = fmaxf(s1, s2);
#pragma unroll
        for (int off = 32; off; off >>= 1) m = fmaxf(m, __shfl_xor(m, off));
        float e1 = __expf(s1 - m);
        float e2 = (c2 < TSTEPS) ? __expf(s2 - m) : 0.f;
        float sum = e1 + e2;
#pragma unroll
        for (int off = 32; off; off >>= 1) sum += __shfl_xor(sum, off);
        float inv = 1.f / sum;
        su[rr][lane] = e1 * inv;
        if (c2 < TSTEPS) su[rr][c2] = e2 * inv;
    }
    __syncthreads();
    float4 acc = make_float4(0.f, 0.f, 0.f, 0.f);
    for (int cc = 0; cc < TSTEPS; ++cc) {
        float a = su[r][cc];
        ushort4 ev = *reinterpret_cast<const ushort4*>(&ehs[((size_t)cc * BATCH + b) * H + l * 4]);
        acc.x += a * bf2f(ev.x); acc.y += a * bf2f(ev.y);
        acc.z += a * bf2f(ev.z); acc.w += a * bf2f(ev.w);
    }
    *reinterpret_cast<float4*>(&deci[(size_t)b * H + l * 4]) = acc;
}

// ---------------- final: out = relu(h@fc1.T) @ fc2.T ----------------
__global__ __launch_bounds__(256) void final_kernel(const float* __restrict__ h,
                                                    const float* __restrict__ fc1,
                                                    const float* __restrict__ fc2,
                                                    float* __restrict__ out) {
    const int b = blockIdx.x;
    __shared__ float hsh[H];
    __shared__ float red[256];
    for (int i = threadIdx.x; i < H; i += 256) hsh[i] = h[(size_t)b * H + i];
    __syncthreads();
    float total = 0.f;
    for (int n = threadIdx.x; n < H; n += 256) {
        float acc = 0.f;
        for (int j = 0; j < H; ++j) acc += fc1[(size_t)n * H + j] * hsh[j];
        total += fmaxf(acc, 0.f) * fc2[n];
    }
    red[threadIdx.x] = total;
    __syncthreads();
    for (int s = 128; s > 0; s >>= 1) {
        if (threadIdx.x < s) red[threadIdx.x] += red[threadIdx.x + s];
        __syncthreads();
    }
    if (threadIdx.x == 0) out[b] = red[0];
}

extern "C" void kernel_launch(void* const* d_in, const int* in_sizes, int n_in,
                              void* d_out, int out_size, void* d_ws, size_t ws_size,
                              hipStream_t stream) {
    const float* x       = (const float*)d_in[0];
    const float* dec_i1  = (const float*)d_in[1];
    const float* W_emb   = (const float*)d_in[2];
    const float* enc_Wih = (const float*)d_in[3];
    const float* enc_Whh = (const float*)d_in[4];
    const float* enc_bih = (const float*)d_in[5];
    const float* enc_bhh = (const float*)d_in[6];
    const float* dec_Wih = (const float*)d_in[7];
    const float* dec_Whh = (const float*)d_in[8];
    const float* dec_bih = (const float*)d_in[9];
    const float* dec_bhh = (const float*)d_in[10];
    const float* W_q     = (const float*)d_in[11];
    const float* W_ref   = (const float*)d_in[12];
    const float* vv      = (const float*)d_in[13];
    const float* fc1     = (const float*)d_in[14];
    const float* fc2     = (const float*)d_in[15];
    float* out = (float*)d_out;

    // workspace layout (f32 unless noted)
    float* hb0 = (float*)d_ws;            // B*H
    float* hb1 = hb0 + BATCH * H;         // B*H
    float* cb  = hb1 + BATCH * H;         // B*H
    float* deci= cb  + BATCH * H;         // B*H
    float* u2  = deci+ BATCH * H;         // B*H
    float* Wc  = u2  + BATCH * H;         // 4H*2
    float* bc  = Wc  + 4 * H * 2;         // 4H
    float* db  = bc  + 4 * H;             // 4H
    __hip_bfloat16* ench = (__hip_bfloat16*)(db + 4 * H);       // T*B*H bf16
    __hip_bfloat16* u1   = ench + (size_t)TSTEPS * BATCH * H;   // T*B*H bf16

    size_t needed = (size_t)((char*)(u1 + (size_t)TSTEPS * BATCH * H) - (char*)d_ws);
    if (ws_size < needed) return;  // insufficient scratch: fail loudly (output stays poisoned)

    float* hb[2] = {hb0, hb1};

    prep_kernel<<<8, 256, 0, stream>>>(W_emb, enc_Wih, enc_bih, enc_bhh, dec_bih, dec_bhh, Wc, bc, db);
    zero_kernel<<<3072, 256, 0, stream>>>(hb0, 3 * BATCH * H);  // hb0, hb1, cb

    for (int t = 0; t < TSTEPS; ++t) {
        lstm_step<1><<<dim3(16, 16), 256, 0, stream>>>(
            x, hb[t & 1], Wc, enc_Whh, bc, cb, hb[(t + 1) & 1],
            ench + (size_t)t * BATCH * H, t);
    }
    // u1 = enc_h @ W_ref.T  (M = T*B, N = H, K = H)
    gemm_nt32<1, 1><<<dim3(TSTEPS * BATCH / 32, H / 32), 256, 0, stream>>>(ench, W_ref, u1, H);

    for (int s = 0; s < TSTEPS; ++s) {
        lstm_step<0><<<dim3(16, 16), 256, 0, stream>>>(
            s == 0 ? dec_i1 : deci, hb[s & 1], dec_Wih, dec_Whh, db, cb,
            hb[(s + 1) & 1], (__hip_bfloat16*)nullptr, 0);
        if (s < TSTEPS - 1) {
            gemm_nt32<0, 0><<<dim3(BATCH / 32, H / 32), 256, 0, stream>>>(hb[(s + 1) & 1], W_q, u2, H);
            attn_step<<<BATCH / 2, 256, 0, stream>>>(u2, u1, ench, vv, deci);
        }
    }
    final_kernel<<<BATCH, 256, 0, stream>>>(hb0, fc1, fc2, out);
}

// Round 2
// 13355.476 us; speedup vs baseline: 2.1956x; 2.1956x over previous
//
#include <hip/hip_runtime.h>
#include <hip/hip_bf16.h>

#define H 512
#define TSTEPS 100
#define BATCH 512
#define KB (H / 32)   // k-blocks of 32 along a 512 contraction dim

typedef __attribute__((ext_vector_type(8))) short bf16x8;
typedef __attribute__((ext_vector_type(4))) float f32x4;
typedef unsigned short u16;

__device__ __forceinline__ float bf2f(u16 u) {
    union { unsigned int i; float f; } z; z.i = ((unsigned int)u) << 16; return z.f;
}
__device__ __forceinline__ u16 f2bf(float f) {
    union { float f; unsigned int u; } z; z.f = f;
    unsigned int r = (z.u + 0x7fffu + ((z.u >> 16) & 1u)) >> 16;
    return (u16)r;
}
__device__ __forceinline__ float sigmoidf_(float x) { return 1.0f / (1.0f + __expf(-x)); }
__device__ __forceinline__ float ftanh(float x) {
    x = fminf(15.0f, fmaxf(-15.0f, x));
    float e = __expf(2.0f * x);
    return (e - 1.0f) / (e + 1.0f);
}

// packed fragment index for a [M x K] bf16 matrix, 16x32 fragments.
// frag id = (m>>4)*kbc + (k>>5); within frag: lane = (m&15) + 16*((kin>>2)&3),
// j = (kin&3) + 4*(kin>>4).  A and B both use this -> k-mapping errors cancel.
__device__ __forceinline__ size_t pidx(int m, int k, int kbc) {
    int kb = k >> 5, kin = k & 31;
    int lane = (m & 15) + (((kin >> 2) & 3) << 4);
    int j = (kin & 3) + ((kin >> 4) << 2);
    return ((size_t)((m >> 4) * kbc + kb) * 64 + lane) * 8 + j;
}

// ---------------- prep: Wc = enc_Wih @ W_emb, combined biases ----------------
__global__ void prep_kernel(const float* __restrict__ W_emb, const float* __restrict__ enc_Wih,
                            const float* __restrict__ enc_bih, const float* __restrict__ enc_bhh,
                            const float* __restrict__ dec_bih, const float* __restrict__ dec_bhh,
                            float* __restrict__ Wc, float* __restrict__ bc, float* __restrict__ db) {
    int g = blockIdx.x * blockDim.x + threadIdx.x;
    if (g >= 4 * H) return;
    float s0 = 0.f, s1 = 0.f;
    for (int j = 0; j < H; ++j) {
        float w = enc_Wih[(size_t)g * H + j];
        s0 += w * W_emb[j * 2 + 0];
        s1 += w * W_emb[j * 2 + 1];
    }
    Wc[g * 2 + 0] = s0; Wc[g * 2 + 1] = s1;
    bc[g] = enc_bih[g] + enc_bhh[g];
    db[g] = dec_bih[g] + dec_bhh[g];
}

// pack f32 [M x 512] into hi/lo bf16 fragment layout
__global__ void pack_w(const float* __restrict__ W, u16* __restrict__ hi, u16* __restrict__ lo,
                       int total) {
    int idx = blockIdx.x * 256 + threadIdx.x;
    if (idx >= total) return;
    int m = idx >> 9, k = idx & 511;   // K = 512 for every packed matrix here
    float v = W[idx];
    u16 h16 = f2bf(v);
    u16 l16 = f2bf(v - bf2f(h16));
    size_t p = pidx(m, k, KB);
    hi[p] = h16; lo[p] = l16;
}

__global__ void zero4(float* __restrict__ p, int n) {
    int i = blockIdx.x * blockDim.x + threadIdx.x;
    if (i < n) p[i] = 0.f;
}

// ---------------- LSTM step via MFMA (split bf16) ----------------
// wave-tile: 16 batch x 16 hidden x 4 gates. grid (B/16, H/16/4), 4 waves/block.
template <int IS_ENC>
__global__ __launch_bounds__(256) void lstm_mfma(
    const u16* __restrict__ A0h, const u16* __restrict__ A0l,   // dec phase0: d (packed)
    const u16* __restrict__ A1h, const u16* __restrict__ A1l,   // h prev (packed)
    const u16* __restrict__ W0h, const u16* __restrict__ W0l,   // dec: Wih packed
    const u16* __restrict__ W1h, const u16* __restrict__ W1l,   // Whh packed
    const float* __restrict__ bias,
    const float* __restrict__ x, const float* __restrict__ Wc,  // enc only
    float* __restrict__ cbuf,
    u16* __restrict__ Hh, u16* __restrict__ Hl,
    u16* __restrict__ ench_row, int t) {
    const int tid = threadIdx.x;
    const int lane = tid & 63;
    const int w = tid >> 6;
    const int m16 = blockIdx.x;                 // batch frag
    const int n16 = blockIdx.y * 4 + w;         // hidden frag (0..31)
    f32x4 acc[4] = {};
    for (int ph = (IS_ENC ? 1 : 0); ph < 2; ++ph) {
        const u16* Ah = ph ? A1h : A0h;
        const u16* Al = ph ? A1l : A0l;
        const u16* Wh = ph ? W1h : W0h;
        const u16* Wl = ph ? W1l : W0l;
#pragma unroll 2
        for (int kb = 0; kb < KB; ++kb) {
            size_t ab = ((size_t)(m16 * KB + kb) * 64 + lane) * 8;
            bf16x8 ah = *(const bf16x8*)&Ah[ab];
            bf16x8 al = *(const bf16x8*)&Al[ab];
#pragma unroll
            for (int q = 0; q < 4; ++q) {
                size_t fb = ((size_t)((q * (H / 16) + n16) * KB + kb) * 64 + lane) * 8;
                bf16x8 bh = *(const bf16x8*)&Wh[fb];
                bf16x8 bl = *(const bf16x8*)&Wl[fb];
                acc[q] = __builtin_amdgcn_mfma_f32_16x16x32_bf16(ah, bh, acc[q], 0, 0, 0);
                acc[q] = __builtin_amdgcn_mfma_f32_16x16x32_bf16(ah, bl, acc[q], 0, 0, 0);
                acc[q] = __builtin_amdgcn_mfma_f32_16x16x32_bf16(al, bh, acc[q], 0, 0, 0);
            }
        }
    }
    const int col = lane & 15, rg = lane >> 4;
    const int n = n16 * 16 + col;
#pragma unroll
    for (int r = 0; r < 4; ++r) {
        int b = m16 * 16 + rg * 4 + r;
        float x0 = 0.f, x1 = 0.f;
        if (IS_ENC) {
            x0 = x[((size_t)b * TSTEPS + t) * 2 + 0];
            x1 = x[((size_t)b * TSTEPS + t) * 2 + 1];
        }
        float g[4];
#pragma unroll
        for (int q = 0; q < 4; ++q) {
            g[q] = acc[q][r] + bias[q * H + n];
            if (IS_ENC) g[q] += x0 * Wc[(q * H + n) * 2 + 0] + x1 * Wc[(q * H + n) * 2 + 1];
        }
        size_t ci = (size_t)b * H + n;
        float cn = sigmoidf_(g[1]) * cbuf[ci] + sigmoidf_(g[0]) * ftanh(g[2]);
        float hn = sigmoidf_(g[3]) * ftanh(cn);
        cbuf[ci] = cn;
        u16 hh = f2bf(hn);
        u16 hl = f2bf(hn - bf2f(hh));
        size_t p = pidx(b, n, KB);
        Hh[p] = hh; Hl[p] = hl;
        if (IS_ENC) ench_row[((size_t)t * BATCH + b) * H + n] = hh;
    }
}

// ---------------- u2 = h @ W_q.T via MFMA, out f32 row-major ----------------
__global__ __launch_bounds__(256) void gemm_u2(const u16* __restrict__ Ah, const u16* __restrict__ Al,
                                               const u16* __restrict__ Bh, const u16* __restrict__ Bl,
                                               float* __restrict__ u2) {
    const int tid = threadIdx.x;
    const int lane = tid & 63;
    const int w = tid >> 6;
    const int m16 = blockIdx.x;
    const int quad = blockIdx.y * 4 + w;   // 0..7, 4 n-frags each
    f32x4 acc[4] = {};
#pragma unroll 2
    for (int kb = 0; kb < KB; ++kb) {
        size_t ab = ((size_t)(m16 * KB + kb) * 64 + lane) * 8;
        bf16x8 ah = *(const bf16x8*)&Ah[ab];
        bf16x8 al = *(const bf16x8*)&Al[ab];
#pragma unroll
        for (int f = 0; f < 4; ++f) {
            int n16 = quad * 4 + f;
            size_t fb = ((size_t)(n16 * KB + kb) * 64 + lane) * 8;
            bf16x8 bh = *(const bf16x8*)&Bh[fb];
            bf16x8 bl = *(const bf16x8*)&Bl[fb];
            acc[f] = __builtin_amdgcn_mfma_f32_16x16x32_bf16(ah, bh, acc[f], 0, 0, 0);
            acc[f] = __builtin_amdgcn_mfma_f32_16x16x32_bf16(ah, bl, acc[f], 0, 0, 0);
            acc[f] = __builtin_amdgcn_mfma_f32_16x16x32_bf16(al, bh, acc[f], 0, 0, 0);
        }
    }
    const int col = lane & 15, rg = lane >> 4;
#pragma unroll
    for (int f = 0; f < 4; ++f) {
        int n = (quad * 4 + f) * 16 + col;
#pragma unroll
        for (int r = 0; r < 4; ++r) {
            int b = m16 * 16 + rg * 4 + r;
            u2[(size_t)b * H + n] = acc[f][r];
        }
    }
}

// ---------------- u1 = ench @ W_ref.T (one-shot). LDS-stage row-major A. ----------------
__global__ __launch_bounds__(256) void gemm_u1(const u16* __restrict__ ench_row,
                                               const u16* __restrict__ Bh, const u16* __restrict__ Bl,
                                               u16* __restrict__ u1_row) {
    __shared__ u16 lds[2 * KB * 64 * 8];   // 32 KB: 2 m-frags x 16 kb, packed layout
    const int tid = threadIdx.x;
    const int m0 = blockIdx.x * 32;
    {
        int r = tid >> 3;       // 0..31 rows
        int o = tid & 7;
#pragma unroll
        for (int p8 = 0; p8 < 8; ++p8) {
            int k0 = (o + 8 * p8) * 8;   // octet base, 0..504
            const u16* src = &ench_row[(size_t)(m0 + r) * H + k0];
            ushort4 v0 = *(const ushort4*)&src[0];
            ushort4 v1 = *(const ushort4*)&src[4];
            int kb = k0 >> 5, kin0 = k0 & 31;
            int g0 = (kin0 >> 2) & 3;      // 0 or 2
            int jo = (kin0 >> 4) << 2;     // 0 or 4
            u16* base = &lds[(size_t)(((r >> 4) * KB + kb) * 64) * 8];
            *(ushort4*)&base[((r & 15) + 16 * g0) * 8 + jo] = v0;
            *(ushort4*)&base[((r & 15) + 16 * (g0 + 1)) * 8 + jo] = v1;
        }
    }
    __syncthreads();
    const int lane = tid & 63;
    const int w = tid >> 6;
    const int mw = w & 1, nh = w >> 1;
    for (int nc = 0; nc < 16; ++nc) {
        int n16 = nh * 16 + nc;
        f32x4 acc = {};
#pragma unroll 4
        for (int kb = 0; kb < KB; ++kb) {
            bf16x8 a = *(const bf16x8*)&lds[((mw * KB + kb) * 64 + lane) * 8];
            size_t fb = ((size_t)(n16 * KB + kb) * 64 + lane) * 8;
            bf16x8 bh = *(const bf16x8*)&Bh[fb];
            bf16x8 bl = *(const bf16x8*)&Bl[fb];
            acc = __builtin_amdgcn_mfma_f32_16x16x32_bf16(a, bh, acc, 0, 0, 0);
            acc = __builtin_amdgcn_mfma_f32_16x16x32_bf16(a, bl, acc, 0, 0, 0);
        }
        const int col = lane & 15, rg = lane >> 4;
#pragma unroll
        for (int r = 0; r < 4; ++r) {
            size_t mrow = (size_t)m0 + mw * 16 + rg * 4 + r;
            u1_row[mrow * H + n16 * 16 + col] = f2bf(acc[r]);
        }
    }
}

// ---------------- attention (row-major u1/ench streams); writes d packed hi/lo ------
__global__ __launch_bounds__(256) void attn_step(const float* __restrict__ u2,
                                                 const u16* __restrict__ u1s,
                                                 const u16* __restrict__ ehs,
                                                 const float* __restrict__ vv,
                                                 u16* __restrict__ dhi, u16* __restrict__ dlo) {
    __shared__ float su2[2][2][TSTEPS];
    __shared__ float su[2][TSTEPS];
    const int tid = threadIdx.x;
    const int r = tid >> 7;        // batch row within tile (0..1)
    const int l = tid & 127;       // 128 threads per row, 4 h each
    const int b = blockIdx.x * 2 + r;
    const int w = (tid >> 6) & 1;  // wave within row
    const float4 u2r = *reinterpret_cast<const float4*>(&u2[(size_t)b * H + l * 4]);
    const float4 vr = *reinterpret_cast<const float4*>(&vv[l * 4]);

    for (int cc = 0; cc < TSTEPS; ++cc) {
        ushort4 uv = *reinterpret_cast<const ushort4*>(&u1s[((size_t)cc * BATCH + b) * H + l * 4]);
        float p = vr.x * ftanh(bf2f(uv.x) + u2r.x)
                + vr.y * ftanh(bf2f(uv.y) + u2r.y)
                + vr.z * ftanh(bf2f(uv.z) + u2r.z)
                + vr.w * ftanh(bf2f(uv.w) + u2r.w);
#pragma unroll
        for (int off = 32; off; off >>= 1) p += __shfl_xor(p, off);
        if ((tid & 63) == 0) su2[r][w][cc] = p;
    }
    __syncthreads();
    if (((tid >> 6) & 1) == 0) {
        const int rr = tid >> 7;
        const int lane = tid & 63;
        const int c2 = lane + 64;
        float s1 = su2[rr][0][lane] + su2[rr][1][lane];
        float s2 = (c2 < TSTEPS) ? (su2[rr][0][c2] + su2[rr][1][c2]) : -1e30f;
        float m = fmaxf(s1, s2);
#pragma unroll
        for (int off = 32; off; off >>= 1) m = fmaxf(m, __shfl_xor(m, off));
        float e1 = __expf(s1 - m);
        float e2 = (c2 < TSTEPS) ? __expf(s2 - m) : 0.f;
        float sum = e1 + e2;
#pragma unroll
        for (int off = 32; off; off >>= 1) sum += __shfl_xor(sum, off);
        float inv = 1.f / sum;
        su[rr][lane] = e1 * inv;
        if (c2 < TSTEPS) su[rr][c2] = e2 * inv;
    }
    __syncthreads();
    float4 acc = make_float4(0.f, 0.f, 0.f, 0.f);
    for (int cc = 0; cc < TSTEPS; ++cc) {
        float a = su[r][cc];
        ushort4 ev = *reinterpret_cast<const ushort4*>(&ehs[((size_t)cc * BATCH + b) * H + l * 4]);
        acc.x += a * bf2f(ev.x); acc.y += a * bf2f(ev.y);
        acc.z += a * bf2f(ev.z); acc.w += a * bf2f(ev.w);
    }
    // write glimpse as packed hi/lo (4 consecutive h share a frag j-run)
    int h0 = l * 4;
    int kin = h0 & 31;
    size_t p = ((size_t)((b >> 4) * KB + (h0 >> 5)) * 64 + (b & 15) + (((kin >> 2) & 3) << 4)) * 8
             + (((kin >> 4) & 1) << 2);
    u16 a0 = f2bf(acc.x), a1 = f2bf(acc.y), a2 = f2bf(acc.z), a3 = f2bf(acc.w);
    *(ushort4*)&dhi[p] = make_ushort4(a0, a1, a2, a3);
    u16 b0 = f2bf(acc.x - bf2f(a0)), b1 = f2bf(acc.y - bf2f(a1));
    u16 b2 = f2bf(acc.z - bf2f(a2)), b3 = f2bf(acc.w - bf2f(a3));
    *(ushort4*)&dlo[p] = make_ushort4(b0, b1, b2, b3);
}

// ---------------- final: out = relu(h@fc1.T) @ fc2.T (h from packed hi/lo) ----------
__global__ __launch_bounds__(256) void final_kernel(const u16* __restrict__ hi,
                                                    const u16* __restrict__ lo,
                                                    const float* __restrict__ fc1,
                                                    const float* __restrict__ fc2,
                                                    float* __restrict__ out) {
    const int b = blockIdx.x;
    __shared__ float hsh[H];
    __shared__ float red[256];
    for (int i = threadIdx.x; i < H; i += 256) {
        size_t p = pidx(b, i, KB);
        hsh[i] = bf2f(hi[p]) + bf2f(lo[p]);
    }
    __syncthreads();
    float total = 0.f;
    for (int n = threadIdx.x; n < H; n += 256) {
        float acc = 0.f;
        for (int j = 0; j < H; ++j) acc += fc1[(size_t)n * H + j] * hsh[j];
        total += fmaxf(acc, 0.f) * fc2[n];
    }
    red[threadIdx.x] = total;
    __syncthreads();
    for (int s = 128; s > 0; s >>= 1) {
        if (threadIdx.x < s) red[threadIdx.x] += red[threadIdx.x + s];
        __syncthreads();
    }
    if (threadIdx.x == 0) out[b] = red[0];
}

extern "C" void kernel_launch(void* const* d_in, const int* in_sizes, int n_in,
                              void* d_out, int out_size, void* d_ws, size_t ws_size,
                              hipStream_t stream) {
    (void)in_sizes; (void)n_in; (void)out_size;
    const float* x       = (const float*)d_in[0];
    const float* dec_i1  = (const float*)d_in[1];
    const float* W_emb   = (const float*)d_in[2];
    const float* enc_Wih = (const float*)d_in[3];
    const float* enc_Whh = (const float*)d_in[4];
    const float* enc_bih = (const float*)d_in[5];
    const float* enc_bhh = (const float*)d_in[6];
    const float* dec_Wih = (const float*)d_in[7];
    const float* dec_Whh = (const float*)d_in[8];
    const float* dec_bih = (const float*)d_in[9];
    const float* dec_bhh = (const float*)d_in[10];
    const float* W_q     = (const float*)d_in[11];
    const float* W_ref   = (const float*)d_in[12];
    const float* vv      = (const float*)d_in[13];
    const float* fc1     = (const float*)d_in[14];
    const float* fc2     = (const float*)d_in[15];
    float* out = (float*)d_out;

    const size_t BH = (size_t)BATCH * H;
    const size_t W4 = (size_t)4 * H * H;
    const size_t WS = (size_t)H * H;
    const size_t TBH = (size_t)TSTEPS * BATCH * H;

    float* c_ = (float*)d_ws;            // BH
    float* u2 = c_ + BH;                 // BH
    float* Wc = u2 + BH;                 // 4H*2
    float* bc = Wc + 4 * H * 2;          // 4H
    float* db = bc + 4 * H;              // 4H
    u16* hbuf  = (u16*)(db + 4 * H);     // 4*BH: hi0, lo0, hi1, lo1
    u16* dhi   = hbuf + 4 * BH;
    u16* dlo   = dhi + BH;
    u16* WeH   = dlo + BH;    u16* WeL  = WeH + W4;     // enc_Whh
    u16* WdiH  = WeL + W4;    u16* WdiL = WdiH + W4;    // dec_Wih
    u16* WdhH  = WdiL + W4;   u16* WdhL = WdhH + W4;    // dec_Whh
    u16* WqH   = WdhL + W4;   u16* WqL  = WqH + WS;     // W_q
    u16* WrH   = WqL + WS;    u16* WrL  = WrH + WS;     // W_ref
    u16* ench  = WrL + WS;                              // TBH row-major
    u16* u1r   = ench + TBH;                            // TBH row-major

    size_t needed = (size_t)((char*)(u1r + TBH) - (char*)d_ws);
    if (ws_size < needed) return;

    u16* hH[2] = {hbuf, hbuf + 2 * BH};
    u16* hL[2] = {hbuf + BH, hbuf + 3 * BH};

    prep_kernel<<<8, 256, 0, stream>>>(W_emb, enc_Wih, enc_bih, enc_bhh, dec_bih, dec_bhh, Wc, bc, db);
    pack_w<<<(int)(W4 / 256), 256, 0, stream>>>(enc_Whh, WeH, WeL, (int)W4);
    pack_w<<<(int)(W4 / 256), 256, 0, stream>>>(dec_Wih, WdiH, WdiL, (int)W4);
    pack_w<<<(int)(W4 / 256), 256, 0, stream>>>(dec_Whh, WdhH, WdhL, (int)W4);
    pack_w<<<(int)(WS / 256), 256, 0, stream>>>(W_q, WqH, WqL, (int)WS);
    pack_w<<<(int)(WS / 256), 256, 0, stream>>>(W_ref, WrH, WrL, (int)WS);
    pack_w<<<(int)(BH / 256), 256, 0, stream>>>(dec_i1, dhi, dlo, (int)BH);
    zero4<<<(int)(BH / 256), 256, 0, stream>>>(c_, (int)BH);
    zero4<<<(int)(2 * BH / 256), 256, 0, stream>>>((float*)hbuf, (int)(2 * BH));  // 4*BH u16

    for (int t = 0; t < TSTEPS; ++t) {
        lstm_mfma<1><<<dim3(BATCH / 16, H / 64), 256, 0, stream>>>(
            nullptr, nullptr, hH[t & 1], hL[t & 1],
            nullptr, nullptr, WeH, WeL,
            bc, x, Wc, c_, hH[(t + 1) & 1], hL[(t + 1) & 1], ench, t);
    }
    gemm_u1<<<TSTEPS * BATCH / 32, 256, 0, stream>>>(ench, WrH, WrL, u1r);

    for (int s = 0; s < TSTEPS; ++s) {
        lstm_mfma<0><<<dim3(BATCH / 16, H / 64), 256, 0, stream>>>(
            dhi, dlo, hH[s & 1], hL[s & 1],
            WdiH, WdiL, WdhH, WdhL,
            db, nullptr, nullptr, c_, hH[(s + 1) & 1], hL[(s + 1) & 1],
            (u16*)nullptr, 0);
        if (s < TSTEPS - 1) {
            gemm_u2<<<dim3(BATCH / 16, 2), 256, 0, stream>>>(hH[(s + 1) & 1], hL[(s + 1) & 1],
                                                             WqH, WqL, u2);
            attn_step<<<BATCH / 2, 256, 0, stream>>>(u2, u1r, ench, vv, dhi, dlo);
        }
    }
    final_kernel<<<BATCH, 256, 0, stream>>>(hH[0], hL[0], fc1, fc2, out);
}